// Round 16
// baseline (39.811 us; speedup 1.0000x reference)
//
#include <hip/hip_runtime.h>
#include <hip/hip_bf16.h>

#define M_TOT 16384   // B*T*H*W = 2*8*32*32
#define D_    256
#define K_DIM 256

typedef __attribute__((ext_vector_type(4))) float f32x4;
typedef __attribute__((ext_vector_type(8))) short s16x8;
typedef __attribute__((ext_vector_type(4))) short s16x4;

typedef const __attribute__((address_space(1))) void* gptr_t;
typedef __attribute__((address_space(3))) void* lptr_t;

__device__ __forceinline__ unsigned short f2bf(float f) {
  unsigned x = __float_as_uint(f);
  return (unsigned short)((x + 0x7fffu + ((x >> 16) & 1u)) >> 16);
}
__device__ __forceinline__ float bf2f(short s) {
  return __uint_as_float(((unsigned)(unsigned short)s) << 16);
}

// ---------- prep: blocks [0,4096) = LayerNorm, [4096,4352) = weight transpose ----------
__global__ __launch_bounds__(256) void prep_kernel(
    const float* __restrict__ x, const float* __restrict__ g, const float* __restrict__ b,
    unsigned short* __restrict__ xn,
    const float* __restrict__ wq, const float* __restrict__ wk,
    const float* __restrict__ wv, const float* __restrict__ wo,
    unsigned short* __restrict__ wt_qkv, unsigned short* __restrict__ wt_o) {
  __shared__ float tile[32][33];
  int tid = threadIdx.x;
  if (blockIdx.x < 4096) {
    int tok  = blockIdx.x * 4 + (tid >> 6);
    int lane = tid & 63;
    f32x4 v = ((const f32x4*)(x + (size_t)tok * D_))[lane];
    float s = 0.f, s2 = 0.f;
#pragma unroll
    for (int i = 0; i < 4; ++i) { s += v[i]; s2 += v[i] * v[i]; }
#pragma unroll
    for (int o = 1; o < 64; o <<= 1) { s += __shfl_xor(s, o); s2 += __shfl_xor(s2, o); }
    float mu   = s * (1.0f / 256.0f);
    float rstd = rsqrtf(s2 * (1.0f / 256.0f) - mu * mu + 1e-5f);
    f32x4 gv = ((const f32x4*)g)[lane];
    f32x4 bv = ((const f32x4*)b)[lane];
    s16x4 o4;
#pragma unroll
    for (int i = 0; i < 4; ++i) o4[i] = (short)f2bf((v[i] - mu) * rstd * gv[i] + bv[i]);
    ((s16x4*)(xn + (size_t)tok * D_))[lane] = o4;
  } else {
    int bid = blockIdx.x - 4096;     // 0..255
    int z   = bid >> 6;              // 0=wq 1=wk 2=wv 3=wo
    int rem = bid & 63;
    int k0 = (rem & 7) * 32, n0 = (rem >> 3) * 32;
    int tx = tid & 31, ty = tid >> 5;  // (32,8)
    const float* src = (z == 0) ? wq : (z == 1) ? wk : (z == 2) ? wv : wo;
#pragma unroll
    for (int i = 0; i < 4; ++i) {
      int r = ty + i * 8;
      tile[r][tx] = src[(size_t)(k0 + r) * D_ + n0 + tx];
    }
    __syncthreads();
    unsigned short* dst = (z < 3) ? (wt_qkv + (size_t)(z * 256 + n0) * K_DIM + k0)
                                  : (wt_o + (size_t)n0 * K_DIM + k0);
#pragma unroll
    for (int i = 0; i < 4; ++i) {
      int r = ty + i * 8;
      dst[(size_t)r * K_DIM + tx] = f2bf(tile[tx][r]);
    }
  }
}

// ---------------- QKV GEMM: C[M][768] = A[M][256] * Bt[768][256]^T -----------
// 128x128 tile, BK=64, 4 waves (2x2). Grid 768, XCD-bijective swizzle. (Champion.)
__global__ __launch_bounds__(256) void gemm_qkv_kernel(
    const unsigned short* __restrict__ A, const unsigned short* __restrict__ Bt,
    const float* __restrict__ b0, const float* __restrict__ b1, const float* __restrict__ b2,
    unsigned short* __restrict__ C) {
  __shared__ __align__(16) char smem[32768];
  char* Asm = smem;            // [128][64] bf16, 128B rows, swizzled
  char* Bsm = smem + 16384;
  const int tid  = threadIdx.x;
  const int wid  = tid >> 6;
  const int lane = tid & 63;
  int lin = blockIdx.y * 6 + blockIdx.x;
  int swz = (lin & 7) * 96 + (lin >> 3);   // 768 blocks, bijective XCD swizzle
  const int m0 = (swz / 6) * 128;
  const int n0 = (swz % 6) * 128;
  const int wave_m = wid >> 1;
  const int wave_n = wid & 1;

  f32x4 acc[4][4] = {};

  for (int ks = 0; ks < 4; ++ks) {
    const int kk0 = ks * 64;
    __syncthreads();
#pragma unroll
    for (int it = 0; it < 4; ++it) {
      int base     = (it * 256 + wid * 64) * 16;
      int lane_lin = base + lane * 16;
      int row  = lane_lin >> 7;
      int off  = lane_lin & 127;
      int soff = off ^ ((row & 7) << 4);
      const char* ga = (const char*)(A + (size_t)(m0 + row) * K_DIM + kk0) + soff;
      const char* gb = (const char*)(Bt + (size_t)(n0 + row) * K_DIM + kk0) + soff;
      __builtin_amdgcn_global_load_lds((gptr_t)ga, (lptr_t)(Asm + base), 16, 0, 0);
      __builtin_amdgcn_global_load_lds((gptr_t)gb, (lptr_t)(Bsm + base), 16, 0, 0);
    }
    __syncthreads();

#pragma unroll
    for (int kk = 0; kk < 2; ++kk) {
      s16x8 af[4], bf[4];
#pragma unroll
      for (int m = 0; m < 4; ++m) {
        int r    = wave_m * 64 + m * 16 + (lane & 15);
        int byte = kk * 64 + ((lane >> 4) * 16);
        af[m] = *(const s16x8*)(Asm + r * 128 + (byte ^ ((r & 7) << 4)));
      }
#pragma unroll
      for (int n = 0; n < 4; ++n) {
        int r    = wave_n * 64 + n * 16 + (lane & 15);
        int byte = kk * 64 + ((lane >> 4) * 16);
        bf[n] = *(const s16x8*)(Bsm + r * 128 + (byte ^ ((r & 7) << 4)));
      }
#pragma unroll
      for (int m = 0; m < 4; ++m)
#pragma unroll
        for (int n = 0; n < 4; ++n)
          acc[m][n] = __builtin_amdgcn_mfma_f32_16x16x32_bf16(af[m], bf[n], acc[m][n], 0, 0, 0);
    }
  }

  const int c0 = lane & 15;
  const int r0 = (lane >> 4) * 4;
#pragma unroll
  for (int m = 0; m < 4; ++m) {
#pragma unroll
    for (int n = 0; n < 4; ++n) {
      int row = m0 + wave_m * 64 + m * 16 + r0;
      int col = n0 + wave_n * 64 + n * 16 + c0;
      const float* bias = (col < 256) ? b0 : (col < 512) ? b1 : b2;
      float bb = bias[col & 255];
#pragma unroll
      for (int r = 0; r < 4; ++r)
        C[(size_t)(row + r) * 768 + col] = f2bf(acc[m][n][r] + bb);
    }
  }
}

// -------- Fused local-attention + output GEMM + bias + residual --------------
// Block = one image row (32 tokens), 512 threads (8 waves). Grid 512 (2/CU).
// Phase 1: Q/K/V in per-wave registers (no block barrier for attention inputs);
//          Bsm0 (ks=0 Wo slice) prefetched via global_load_lds under phase 1.
// Phase 2: DOUBLE-BUFFERED Bsm, stage(ks+1) issued BEFORE compute(ks),
//          ONE barrier per K-step. LDS 80KB = Asm 16K + Bsm0 32K + Bsm1 32K.
__global__ __launch_bounds__(512, 4) void attn_ogemm_kernel(
    const unsigned short* __restrict__ qkv, const unsigned short* __restrict__ wto,
    const float* __restrict__ bo, const float* __restrict__ x,
    float* __restrict__ out) {
  __shared__ __align__(16) char smem[81920];
  char* Asm  = smem;            // [32 tok][512B], XOR-swizzled
  char* Bsm0 = smem + 16384;    // [128][128B] Wo K-slice, swizzled
  char* Bsm1 = smem + 49152;
  const int tid  = threadIdx.x;
  const int wid  = tid >> 6;
  const int lane = tid & 63;
  int bswz = (blockIdx.x & 7) * 64 + (blockIdx.x >> 3);
  const int bt = bswz >> 5;
  const int h  = bswz & 31;
  const int t0 = bswz * 32;
  const size_t img = (size_t)bt << 10;

  int srow[3];
  srow[0] = max(h - 1, 0); srow[1] = h; srow[2] = min(h + 1, 31);

  // ---- stage helper pattern (static ks) ----
#define STAGE_B(KS, DST)                                                        \
  {                                                                             \
    _Pragma("unroll")                                                           \
    for (int it = 0; it < 4; ++it) {                                            \
      int base     = it * 8192 + wid * 1024;                                    \
      int lane_lin = base + lane * 16;                                          \
      int row  = lane_lin >> 7;                                                 \
      int off  = lane_lin & 127;                                                \
      int soff = off ^ ((row & 7) << 4);                                        \
      const char* gb = (const char*)(wto + (size_t)row * K_DIM + (KS)*64) + soff; \
      __builtin_amdgcn_global_load_lds((gptr_t)gb, (lptr_t)((DST) + base), 16, 0, 0); \
    }                                                                           \
  }

  // ---- prefetch Bsm0 for ks=0 (hidden under all of phase 1) ----
  STAGE_B(0, Bsm0);

  // ---- per-wave register loads: Q (4 rows), K (3x6), V (3x6) — coalesced ----
  s16x4 qr4[4];
#pragma unroll
  for (int i = 0; i < 4; ++i)
    qr4[i] = *(const s16x4*)(qkv + (size_t)(t0 + wid * 4 + i) * 768 + lane * 4);
  s16x4 kreg[3][6], vreg[3][6];
#pragma unroll
  for (int s = 0; s < 3; ++s) {
#pragma unroll
    for (int cr = 0; cr < 6; ++cr) {
      int cc = min(max(wid * 4 - 1 + cr, 0), 31);
      const unsigned short* rowp = qkv + (img + (size_t)srow[s] * 32 + cc) * 768;
      kreg[s][cr] = *(const s16x4*)(rowp + 256 + lane * 4);
      vreg[s][cr] = *(const s16x4*)(rowp + 512 + lane * 4);
    }
  }

  // ---- scores + softmax + PV per token, all from registers ----
#pragma unroll
  for (int i = 0; i < 4; ++i) {
    f32x4 q;
#pragma unroll
    for (int e = 0; e < 4; ++e) q[e] = bf2f(qr4[i][e]);
    float sc[9];
#pragma unroll
    for (int s = 0; s < 3; ++s) {
#pragma unroll
      for (int dw = -1; dw <= 1; ++dw) {
        const int j = s * 3 + (dw + 1);
        s16x4 kr = kreg[s][i + dw + 1];   // static index; cc pre-clamped at load
        float p = 0.f;
#pragma unroll
        for (int e = 0; e < 4; ++e) p += q[e] * bf2f(kr[e]);
        p += __shfl_xor(p, 1);
        p += __shfl_xor(p, 2);
        p += __shfl_xor(p, 4);
        sc[j] = p * 0.17677669529663687f;  // 1/sqrt(32)
      }
    }
    float mx = sc[0];
#pragma unroll
    for (int j = 1; j < 9; ++j) mx = fmaxf(mx, sc[j]);
    float den = 0.f;
#pragma unroll
    for (int j = 0; j < 9; ++j) { sc[j] = __expf(sc[j] - mx); den += sc[j]; }
    float inv = 1.0f / den;
    f32x4 o = {};
#pragma unroll
    for (int s = 0; s < 3; ++s) {
#pragma unroll
      for (int dw = -1; dw <= 1; ++dw) {
        const int j = s * 3 + (dw + 1);
        float wj = sc[j] * inv;
        s16x4 vr = vreg[s][i + dw + 1];   // static index
#pragma unroll
        for (int e = 0; e < 4; ++e) o[e] += wj * bf2f(vr[e]);
      }
    }
    int tloc = wid * 4 + i;
    s16x4 ov;
#pragma unroll
    for (int e = 0; e < 4; ++e) ov[e] = (short)f2bf(o[e]);
    int byte = (lane * 8) ^ ((tloc & 7) << 4);
    *(s16x4*)(Asm + tloc * 512 + byte) = ov;
  }
  __syncthreads();  // Asm visible + Bsm0 staged

  // ---- Phase 2: dbuf out-GEMM, stage-before-compute, 1 barrier/step ----
  const int wave_m = wid >> 2;
  const int wave_n = wid & 3;
  f32x4 acc[4] = {};

#define COMP_B(KS, BUF)                                                         \
  {                                                                             \
    _Pragma("unroll")                                                           \
    for (int kk = 0; kk < 2; ++kk) {                                            \
      s16x8 af, bf[4];                                                          \
      {                                                                         \
        int r    = wave_m * 16 + (lane & 15);                                   \
        int byte = (KS)*128 + kk * 64 + ((lane >> 4) * 16);                     \
        af = *(const s16x8*)(Asm + r * 512 + (byte ^ ((r & 7) << 4)));          \
      }                                                                         \
      _Pragma("unroll")                                                         \
      for (int n = 0; n < 4; ++n) {                                             \
        int r    = wave_n * 64 + n * 16 + (lane & 15);                          \
        int byte = kk * 64 + ((lane >> 4) * 16);                                \
        bf[n] = *(const s16x8*)((BUF) + r * 128 + (byte ^ ((r & 7) << 4)));     \
      }                                                                         \
      _Pragma("unroll")                                                         \
      for (int n = 0; n < 4; ++n)                                               \
        acc[n] = __builtin_amdgcn_mfma_f32_16x16x32_bf16(af, bf[n], acc[n], 0, 0, 0); \
    }                                                                           \
  }

  STAGE_B(1, Bsm1);
  COMP_B(0, Bsm0);
  __syncthreads();   // drains stage(1); all reads of Bsm0 done
  STAGE_B(2, Bsm0);
  COMP_B(1, Bsm1);
  __syncthreads();   // drains stage(2); all reads of Bsm1 done
  STAGE_B(3, Bsm1);
  COMP_B(2, Bsm0);
  __syncthreads();   // drains stage(3)
  COMP_B(3, Bsm1);

#undef STAGE_B
#undef COMP_B

  const int c0 = lane & 15;
  const int r0 = (lane >> 4) * 4;
#pragma unroll
  for (int n = 0; n < 4; ++n) {
    int col = wave_n * 64 + n * 16 + c0;
    float bb = bo[col];
#pragma unroll
    for (int r = 0; r < 4; ++r) {
      int row = t0 + wave_m * 16 + r0 + r;
      out[(size_t)row * D_ + col] = acc[n][r] + bb + x[(size_t)row * D_ + col];
    }
  }
}

extern "C" void kernel_launch(void* const* d_in, const int* in_sizes, int n_in,
                              void* d_out, int out_size, void* d_ws, size_t ws_size,
                              hipStream_t stream) {
  const float* x  = (const float*)d_in[0];
  const float* lg = (const float*)d_in[1];
  const float* lb = (const float*)d_in[2];
  const float* wq = (const float*)d_in[3];
  const float* bq = (const float*)d_in[4];
  const float* wk = (const float*)d_in[5];
  const float* bk = (const float*)d_in[6];
  const float* wv = (const float*)d_in[7];
  const float* bv = (const float*)d_in[8];
  const float* wo = (const float*)d_in[9];
  const float* bo = (const float*)d_in[10];
  float* out = (float*)d_out;

  char* ws = (char*)d_ws;
  unsigned short* xn    = (unsigned short*)ws;                 // 16384*256*2
  unsigned short* qkv   = (unsigned short*)(ws + 8388608);     // 16384*768*2
  unsigned short* wtqkv = (unsigned short*)(ws + 33554432);    // 768*256*2
  unsigned short* wto   = (unsigned short*)(ws + 33947648);    // 256*256*2

  prep_kernel<<<4352, 256, 0, stream>>>(x, lg, lb, xn, wq, wk, wv, wo, wtqkv, wto);
  gemm_qkv_kernel<<<dim3(6, 128), 256, 0, stream>>>(xn, wtqkv, bq, bk, bv, qkv);
  attn_ogemm_kernel<<<512, 512, 0, stream>>>(qkv, wto, bo, x, out);
}

// Round 17
// 39.621 us; speedup vs baseline: 1.0048x; 1.0048x over previous
//
#include <hip/hip_runtime.h>
#include <hip/hip_bf16.h>

#define M_TOT 16384   // B*T*H*W = 2*8*32*32
#define D_    256
#define K_DIM 256

typedef __attribute__((ext_vector_type(4))) float f32x4;
typedef __attribute__((ext_vector_type(8))) short s16x8;
typedef __attribute__((ext_vector_type(4))) short s16x4;

typedef const __attribute__((address_space(1))) void* gptr_t;
typedef __attribute__((address_space(3))) void* lptr_t;

__device__ __forceinline__ unsigned short f2bf(float f) {
  unsigned x = __float_as_uint(f);
  return (unsigned short)((x + 0x7fffu + ((x >> 16) & 1u)) >> 16);
}
__device__ __forceinline__ float bf2f(short s) {
  return __uint_as_float(((unsigned)(unsigned short)s) << 16);
}

// ---------- prep: blocks [0,4096) = LayerNorm, [4096,4352) = weight transpose ----------
__global__ __launch_bounds__(256) void prep_kernel(
    const float* __restrict__ x, const float* __restrict__ g, const float* __restrict__ b,
    unsigned short* __restrict__ xn,
    const float* __restrict__ wq, const float* __restrict__ wk,
    const float* __restrict__ wv, const float* __restrict__ wo,
    unsigned short* __restrict__ wt_qkv, unsigned short* __restrict__ wt_o) {
  __shared__ float tile[32][33];
  int tid = threadIdx.x;
  if (blockIdx.x < 4096) {
    int tok  = blockIdx.x * 4 + (tid >> 6);
    int lane = tid & 63;
    f32x4 v = ((const f32x4*)(x + (size_t)tok * D_))[lane];
    float s = 0.f, s2 = 0.f;
#pragma unroll
    for (int i = 0; i < 4; ++i) { s += v[i]; s2 += v[i] * v[i]; }
#pragma unroll
    for (int o = 1; o < 64; o <<= 1) { s += __shfl_xor(s, o); s2 += __shfl_xor(s2, o); }
    float mu   = s * (1.0f / 256.0f);
    float rstd = rsqrtf(s2 * (1.0f / 256.0f) - mu * mu + 1e-5f);
    f32x4 gv = ((const f32x4*)g)[lane];
    f32x4 bv = ((const f32x4*)b)[lane];
    s16x4 o4;
#pragma unroll
    for (int i = 0; i < 4; ++i) o4[i] = (short)f2bf((v[i] - mu) * rstd * gv[i] + bv[i]);
    ((s16x4*)(xn + (size_t)tok * D_))[lane] = o4;
  } else {
    int bid = blockIdx.x - 4096;     // 0..255
    int z   = bid >> 6;              // 0=wq 1=wk 2=wv 3=wo
    int rem = bid & 63;
    int k0 = (rem & 7) * 32, n0 = (rem >> 3) * 32;
    int tx = tid & 31, ty = tid >> 5;  // (32,8)
    const float* src = (z == 0) ? wq : (z == 1) ? wk : (z == 2) ? wv : wo;
#pragma unroll
    for (int i = 0; i < 4; ++i) {
      int r = ty + i * 8;
      tile[r][tx] = src[(size_t)(k0 + r) * D_ + n0 + tx];
    }
    __syncthreads();
    unsigned short* dst = (z < 3) ? (wt_qkv + (size_t)(z * 256 + n0) * K_DIM + k0)
                                  : (wt_o + (size_t)n0 * K_DIM + k0);
#pragma unroll
    for (int i = 0; i < 4; ++i) {
      int r = ty + i * 8;
      dst[(size_t)r * K_DIM + tx] = f2bf(tile[tx][r]);
    }
  }
}

// ---------------- QKV GEMM: C[M][768] = A[M][256] * Bt[768][256]^T -----------
// 128x128 tile, BK=64, 4 waves (2x2). Grid 768, XCD-bijective swizzle. (Champion.)
__global__ __launch_bounds__(256) void gemm_qkv_kernel(
    const unsigned short* __restrict__ A, const unsigned short* __restrict__ Bt,
    const float* __restrict__ b0, const float* __restrict__ b1, const float* __restrict__ b2,
    unsigned short* __restrict__ C) {
  __shared__ __align__(16) char smem[32768];
  char* Asm = smem;            // [128][64] bf16, 128B rows, swizzled
  char* Bsm = smem + 16384;
  const int tid  = threadIdx.x;
  const int wid  = tid >> 6;
  const int lane = tid & 63;
  int lin = blockIdx.y * 6 + blockIdx.x;
  int swz = (lin & 7) * 96 + (lin >> 3);   // 768 blocks, bijective XCD swizzle
  const int m0 = (swz / 6) * 128;
  const int n0 = (swz % 6) * 128;
  const int wave_m = wid >> 1;
  const int wave_n = wid & 1;

  f32x4 acc[4][4] = {};

  for (int ks = 0; ks < 4; ++ks) {
    const int kk0 = ks * 64;
    __syncthreads();
#pragma unroll
    for (int it = 0; it < 4; ++it) {
      int base     = (it * 256 + wid * 64) * 16;
      int lane_lin = base + lane * 16;
      int row  = lane_lin >> 7;
      int off  = lane_lin & 127;
      int soff = off ^ ((row & 7) << 4);
      const char* ga = (const char*)(A + (size_t)(m0 + row) * K_DIM + kk0) + soff;
      const char* gb = (const char*)(Bt + (size_t)(n0 + row) * K_DIM + kk0) + soff;
      __builtin_amdgcn_global_load_lds((gptr_t)ga, (lptr_t)(Asm + base), 16, 0, 0);
      __builtin_amdgcn_global_load_lds((gptr_t)gb, (lptr_t)(Bsm + base), 16, 0, 0);
    }
    __syncthreads();

#pragma unroll
    for (int kk = 0; kk < 2; ++kk) {
      s16x8 af[4], bf[4];
#pragma unroll
      for (int m = 0; m < 4; ++m) {
        int r    = wave_m * 64 + m * 16 + (lane & 15);
        int byte = kk * 64 + ((lane >> 4) * 16);
        af[m] = *(const s16x8*)(Asm + r * 128 + (byte ^ ((r & 7) << 4)));
      }
#pragma unroll
      for (int n = 0; n < 4; ++n) {
        int r    = wave_n * 64 + n * 16 + (lane & 15);
        int byte = kk * 64 + ((lane >> 4) * 16);
        bf[n] = *(const s16x8*)(Bsm + r * 128 + (byte ^ ((r & 7) << 4)));
      }
#pragma unroll
      for (int m = 0; m < 4; ++m)
#pragma unroll
        for (int n = 0; n < 4; ++n)
          acc[m][n] = __builtin_amdgcn_mfma_f32_16x16x32_bf16(af[m], bf[n], acc[m][n], 0, 0, 0);
    }
  }

  const int c0 = lane & 15;
  const int r0 = (lane >> 4) * 4;
#pragma unroll
  for (int m = 0; m < 4; ++m) {
#pragma unroll
    for (int n = 0; n < 4; ++n) {
      int row = m0 + wave_m * 64 + m * 16 + r0;
      int col = n0 + wave_n * 64 + n * 16 + c0;
      const float* bias = (col < 256) ? b0 : (col < 512) ? b1 : b2;
      float bb = bias[col & 255];
#pragma unroll
      for (int r = 0; r < 4; ++r)
        C[(size_t)(row + r) * 768 + col] = f2bf(acc[m][n][r] + bb);
    }
  }
}

// -------- Fused local-attention + output GEMM + bias + residual --------------
// Block = one image row (32 tokens), 512 threads (8 waves). Grid 512 (2/CU).
// Phase 1: Q/K/V in per-wave registers (no block barrier for attention inputs);
//          Bsm (ks=0 Wo slice) prefetched via global_load_lds under phase 1.
// Phase 2: C[32][256] = Asm @ Wo^T; LDS = Asm 16KB + Bsm 32KB = 48KB. (Champion.)
__global__ __launch_bounds__(512, 4) void attn_ogemm_kernel(
    const unsigned short* __restrict__ qkv, const unsigned short* __restrict__ wto,
    const float* __restrict__ bo, const float* __restrict__ x,
    float* __restrict__ out) {
  __shared__ __align__(16) char smem[49152];
  char* Asm = smem;            // [32 tok][512B], XOR-swizzled
  char* Bsm = smem + 16384;    // [128][128B] Wo K-slice, swizzled
  const int tid  = threadIdx.x;
  const int wid  = tid >> 6;
  const int lane = tid & 63;
  int bswz = (blockIdx.x & 7) * 64 + (blockIdx.x >> 3);
  const int bt = bswz >> 5;
  const int h  = bswz & 31;
  const int t0 = bswz * 32;
  const size_t img = (size_t)bt << 10;

  int srow[3];
  srow[0] = max(h - 1, 0); srow[1] = h; srow[2] = min(h + 1, 31);

  // ---- prefetch Bsm for ks=0 (hidden under all of phase 1) ----
#pragma unroll
  for (int it = 0; it < 4; ++it) {
    int base     = it * 8192 + wid * 1024;
    int lane_lin = base + lane * 16;
    int row  = lane_lin >> 7;
    int off  = lane_lin & 127;
    int soff = off ^ ((row & 7) << 4);
    const char* gb = (const char*)(wto + (size_t)row * K_DIM + 0) + soff;
    __builtin_amdgcn_global_load_lds((gptr_t)gb, (lptr_t)(Bsm + base), 16, 0, 0);
  }

  // ---- per-wave register loads: Q (4 rows), K (3x6), V (3x6) — coalesced ----
  s16x4 qr4[4];
#pragma unroll
  for (int i = 0; i < 4; ++i)
    qr4[i] = *(const s16x4*)(qkv + (size_t)(t0 + wid * 4 + i) * 768 + lane * 4);
  s16x4 kreg[3][6], vreg[3][6];
#pragma unroll
  for (int s = 0; s < 3; ++s) {
#pragma unroll
    for (int cr = 0; cr < 6; ++cr) {
      int cc = min(max(wid * 4 - 1 + cr, 0), 31);
      const unsigned short* rowp = qkv + (img + (size_t)srow[s] * 32 + cc) * 768;
      kreg[s][cr] = *(const s16x4*)(rowp + 256 + lane * 4);
      vreg[s][cr] = *(const s16x4*)(rowp + 512 + lane * 4);
    }
  }

  // ---- scores + softmax + PV per token, all from registers ----
#pragma unroll
  for (int i = 0; i < 4; ++i) {
    f32x4 q;
#pragma unroll
    for (int e = 0; e < 4; ++e) q[e] = bf2f(qr4[i][e]);
    float sc[9];
#pragma unroll
    for (int s = 0; s < 3; ++s) {
#pragma unroll
      for (int dw = -1; dw <= 1; ++dw) {
        const int j = s * 3 + (dw + 1);
        s16x4 kr = kreg[s][i + dw + 1];   // static index; cc pre-clamped at load
        float p = 0.f;
#pragma unroll
        for (int e = 0; e < 4; ++e) p += q[e] * bf2f(kr[e]);
        p += __shfl_xor(p, 1);
        p += __shfl_xor(p, 2);
        p += __shfl_xor(p, 4);
        sc[j] = p * 0.17677669529663687f;  // 1/sqrt(32)
      }
    }
    float mx = sc[0];
#pragma unroll
    for (int j = 1; j < 9; ++j) mx = fmaxf(mx, sc[j]);
    float den = 0.f;
#pragma unroll
    for (int j = 0; j < 9; ++j) { sc[j] = __expf(sc[j] - mx); den += sc[j]; }
    float inv = 1.0f / den;
    f32x4 o = {};
#pragma unroll
    for (int s = 0; s < 3; ++s) {
#pragma unroll
      for (int dw = -1; dw <= 1; ++dw) {
        const int j = s * 3 + (dw + 1);
        float wj = sc[j] * inv;
        s16x4 vr = vreg[s][i + dw + 1];   // static index
#pragma unroll
        for (int e = 0; e < 4; ++e) o[e] += wj * bf2f(vr[e]);
      }
    }
    int tloc = wid * 4 + i;
    s16x4 ov;
#pragma unroll
    for (int e = 0; e < 4; ++e) ov[e] = (short)f2bf(o[e]);
    int byte = (lane * 8) ^ ((tloc & 7) << 4);
    *(s16x4*)(Asm + tloc * 512 + byte) = ov;
  }
  __syncthreads();  // Asm visible + Bsm(ks=0) staged

  // ---- Phase 2: out-GEMM. 8 waves = 2(m) x 4(n); wave-tile 16x64 ----
  const int wave_m = wid >> 2;
  const int wave_n = wid & 3;
  f32x4 acc[4] = {};

  for (int ks = 0; ks < 4; ++ks) {
#pragma unroll
    for (int kk = 0; kk < 2; ++kk) {
      s16x8 af, bf[4];
      {
        int r    = wave_m * 16 + (lane & 15);
        int byte = ks * 128 + kk * 64 + ((lane >> 4) * 16);
        af = *(const s16x8*)(Asm + r * 512 + (byte ^ ((r & 7) << 4)));
      }
#pragma unroll
      for (int n = 0; n < 4; ++n) {
        int r    = wave_n * 64 + n * 16 + (lane & 15);
        int byte = kk * 64 + ((lane >> 4) * 16);
        bf[n] = *(const s16x8*)(Bsm + r * 128 + (byte ^ ((r & 7) << 4)));
      }
#pragma unroll
      for (int n = 0; n < 4; ++n)
        acc[n] = __builtin_amdgcn_mfma_f32_16x16x32_bf16(af, bf[n], acc[n], 0, 0, 0);
    }
    if (ks < 3) {
      __syncthreads();  // all Bsm reads done
#pragma unroll
      for (int it = 0; it < 4; ++it) {
        int base     = it * 8192 + wid * 1024;
        int lane_lin = base + lane * 16;
        int row  = lane_lin >> 7;
        int off  = lane_lin & 127;
        int soff = off ^ ((row & 7) << 4);
        const char* gb = (const char*)(wto + (size_t)row * K_DIM + (ks + 1) * 64) + soff;
        __builtin_amdgcn_global_load_lds((gptr_t)gb, (lptr_t)(Bsm + base), 16, 0, 0);
      }
      __syncthreads();  // staged
    }
  }

  const int c0 = lane & 15;
  const int r0 = (lane >> 4) * 4;
#pragma unroll
  for (int n = 0; n < 4; ++n) {
    int col = wave_n * 64 + n * 16 + c0;
    float bb = bo[col];
#pragma unroll
    for (int r = 0; r < 4; ++r) {
      int row = t0 + wave_m * 16 + r0 + r;
      out[(size_t)row * D_ + col] = acc[n][r] + bb + x[(size_t)row * D_ + col];
    }
  }
}

extern "C" void kernel_launch(void* const* d_in, const int* in_sizes, int n_in,
                              void* d_out, int out_size, void* d_ws, size_t ws_size,
                              hipStream_t stream) {
  const float* x  = (const float*)d_in[0];
  const float* lg = (const float*)d_in[1];
  const float* lb = (const float*)d_in[2];
  const float* wq = (const float*)d_in[3];
  const float* bq = (const float*)d_in[4];
  const float* wk = (const float*)d_in[5];
  const float* bk = (const float*)d_in[6];
  const float* wv = (const float*)d_in[7];
  const float* bv = (const float*)d_in[8];
  const float* wo = (const float*)d_in[9];
  const float* bo = (const float*)d_in[10];
  float* out = (float*)d_out;

  char* ws = (char*)d_ws;
  unsigned short* xn    = (unsigned short*)ws;                 // 16384*256*2
  unsigned short* qkv   = (unsigned short*)(ws + 8388608);     // 16384*768*2
  unsigned short* wtqkv = (unsigned short*)(ws + 33554432);    // 768*256*2
  unsigned short* wto   = (unsigned short*)(ws + 33947648);    // 256*256*2

  prep_kernel<<<4352, 256, 0, stream>>>(x, lg, lb, xn, wq, wk, wv, wo, wtqkv, wto);
  gemm_qkv_kernel<<<dim3(6, 128), 256, 0, stream>>>(xn, wtqkv, bq, bk, bv, qkv);
  attn_ogemm_kernel<<<512, 512, 0, stream>>>(qkv, wto, bo, x, out);
}